// Round 1
// baseline (697.983 us; speedup 1.0000x reference)
//
#include <hip/hip_runtime.h>
#include <math.h>

#define BB 64
#define E_PER 4096
#define DD 256
#define KK 50
#define EE (BB * E_PER)

// ---------------------------------------------------------------------------
// Kernel 1: per-edge score. One 64-lane wave per edge; lane i owns dims
// [4i, 4i+4) as a float4 -> 64 lanes x 16B = 1 KB coalesced per stream.
// score = -( |w0|*rel_loss + |w1|*sample_loss + |w2|*triple_loss )
// Linear in per-dim terms, so fold weights in BEFORE the wave reduction:
// p_lane = |w0|*sum|qr-r| + |w2|*sum|qs+r-vj|  (over the lane's 4 dims)
// ---------------------------------------------------------------------------
__global__ __launch_bounds__(256) void score_kernel(
    const float* __restrict__ w3,          // step_score_add_all (3)
    const float* __restrict__ sample_loss, // (E)
    const float* __restrict__ vj,          // node_rep_vj (E,D)
    const float* __restrict__ rel,         // rel_emb     (E,D)
    const float* __restrict__ qsrc,        // query_src_ts_emb (B,D)
    const float* __restrict__ qrel,        // query_rel_emb    (B,D)
    const int*   __restrict__ edges,       // selected_edges (E,9)
    float* __restrict__ score_out)         // (E)
{
    const int gwave = (blockIdx.x * blockDim.x + threadIdx.x) >> 6;
    const int lane  = threadIdx.x & 63;
    if (gwave >= EE) return;
    const int e = gwave;
    const int b = edges[(size_t)e * 9 + 8];   // qidx

    const float4 r  = ((const float4*)(rel  + (size_t)e * DD))[lane];
    const float4 v  = ((const float4*)(vj   + (size_t)e * DD))[lane];
    const float4 qs = ((const float4*)(qsrc + (size_t)b * DD))[lane];
    const float4 qr = ((const float4*)(qrel + (size_t)b * DD))[lane];

    const float w0 = fabsf(w3[0]);
    const float w1 = fabsf(w3[1]);
    const float w2 = fabsf(w3[2]);

    float relp = fabsf(qr.x - r.x) + fabsf(qr.y - r.y) +
                 fabsf(qr.z - r.z) + fabsf(qr.w - r.w);
    float trip = fabsf(qs.x + r.x - v.x) + fabsf(qs.y + r.y - v.y) +
                 fabsf(qs.z + r.z - v.z) + fabsf(qs.w + r.w - v.w);

    float p = w0 * relp + w2 * trip;
    #pragma unroll
    for (int m = 1; m < 64; m <<= 1) p += __shfl_xor(p, m, 64);

    if (lane == 0) score_out[e] = -(p + w1 * sample_loss[e]);
}

// ---------------------------------------------------------------------------
// Kernel 2: passthrough copy of visited_nodes_reg (E floats) as float4.
// ---------------------------------------------------------------------------
__global__ __launch_bounds__(256) void copy_kernel(
    const float* __restrict__ in, float* __restrict__ out)
{
    const int i = blockIdx.x * blockDim.x + threadIdx.x;
    if (i < EE / 4) ((float4*)out)[i] = ((const float4*)in)[i];
}

// ---------------------------------------------------------------------------
// Kernel 3: per-row top-50 (descending, ties -> smaller index, matching
// jax.lax.top_k). One block per batch row; 4096 scores live in LDS; 50x
// iterative argmax (thread-local scan stride-256 = 2 lanes/bank = free).
// Then write pruned_edges and orig_indices as float32 VALUES (harness reads
// the concatenated output buffer as fp32; indices < 2^24 are exact).
// ---------------------------------------------------------------------------
__global__ __launch_bounds__(256) void topk_kernel(
    const float* __restrict__ scores,   // (B, E_PER) = target_score
    const int*   __restrict__ edges,    // selected_edges (E,9)
    float* __restrict__ pruned_out,     // (B*K*9) floats
    float* __restrict__ orig_out)       // (B*K)   floats
{
    __shared__ float s_val[E_PER];
    __shared__ float s_red_v[4];
    __shared__ int   s_red_i[4];
    __shared__ int   s_sel[KK];

    const int b   = blockIdx.x;
    const int tid = threadIdx.x;

    const float4* src = (const float4*)(scores + (size_t)b * E_PER);
    for (int i = tid; i < E_PER / 4; i += 256)
        ((float4*)s_val)[i] = src[i];
    __syncthreads();

    const int lane = tid & 63;
    const int wid  = tid >> 6;

    for (int k = 0; k < KK; ++k) {
        float bv = -INFINITY;
        int   bi = 0x7fffffff;
        for (int i = tid; i < E_PER; i += 256) {
            float v = s_val[i];
            if (v > bv) { bv = v; bi = i; }   // ascending scan + strict > => smallest idx on tie
        }
        #pragma unroll
        for (int m = 1; m < 64; m <<= 1) {
            float ov = __shfl_xor(bv, m, 64);
            int   oi = __shfl_xor(bi, m, 64);
            if (ov > bv || (ov == bv && oi < bi)) { bv = ov; bi = oi; }
        }
        if (lane == 0) { s_red_v[wid] = bv; s_red_i[wid] = bi; }
        __syncthreads();
        if (tid == 0) {
            float fv = s_red_v[0]; int fi = s_red_i[0];
            #pragma unroll
            for (int w = 1; w < 4; ++w) {
                if (s_red_v[w] > fv || (s_red_v[w] == fv && s_red_i[w] < fi)) {
                    fv = s_red_v[w]; fi = s_red_i[w];
                }
            }
            s_sel[k] = fi;
            s_val[fi] = -INFINITY;   // remove from next rounds
        }
        __syncthreads();
    }

    // pruned_edges: (B*K, 9) gather, written as float values
    for (int t = tid; t < KK * 9; t += 256) {
        const int k = t / 9, j = t % 9;
        const int orig = b * E_PER + s_sel[k];
        pruned_out[(size_t)(b * KK + k) * 9 + j] = (float)edges[(size_t)orig * 9 + j];
    }
    // orig_indices, as float values
    for (int t = tid; t < KK; t += 256)
        orig_out[b * KK + t] = (float)(b * E_PER + s_sel[t]);
}

extern "C" void kernel_launch(void* const* d_in, const int* in_sizes, int n_in,
                              void* d_out, int out_size, void* d_ws, size_t ws_size,
                              hipStream_t stream) {
    const float* w        = (const float*)d_in[0];  // step_score_add_all (3,1)
    const float* visited  = (const float*)d_in[1];  // visited_nodes_reg (E)
    // d_in[2] src_ts_emb_special_set  -- unused by reference
    const float* sample   = (const float*)d_in[3];  // sample_loss (E)
    // d_in[4] node_rep_vi             -- unused by reference
    const float* vj       = (const float*)d_in[5];  // node_rep_vj (E,D)
    const float* rel      = (const float*)d_in[6];  // rel_emb (E,D)
    const float* qsrc     = (const float*)d_in[7];  // query_src_ts_emb (B,D)
    const float* qrel     = (const float*)d_in[8];  // query_rel_emb (B,D)
    const int*   edges    = (const int*)d_in[9];    // selected_edges (E,9)
    // d_in[10] max_edges = 50 (compile-time KK)

    float* out        = (float*)d_out;
    float* score_out  = out;                         // (E)
    float* visited_out= out + EE;                    // (E)
    float* pruned_out = out + 2 * EE;                // (B*K*9)
    float* orig_out   = out + 2 * EE + BB * KK * 9;  // (B*K)

    // one wave per edge -> E waves -> E/4 blocks of 256 threads
    score_kernel<<<EE / 4, 256, 0, stream>>>(w, sample, vj, rel, qsrc, qrel,
                                             edges, score_out);
    copy_kernel<<<(EE / 4 + 255) / 256, 256, 0, stream>>>(visited, visited_out);
    topk_kernel<<<BB, 256, 0, stream>>>(score_out, edges, pruned_out, orig_out);
}